// Round 1
// baseline (262.952 us; speedup 1.0000x reference)
//
#include <hip/hip_runtime.h>

#define TPB 256

typedef unsigned short u16;
typedef short short8 __attribute__((ext_vector_type(8)));
typedef float f32x4 __attribute__((ext_vector_type(4)));

__device__ __forceinline__ u16 f2bf(float x) {
  union { float f; unsigned int u; } v;
  v.f = x;
  unsigned int r = v.u + 0x7FFFu + ((v.u >> 16) & 1u);
  return (u16)(r >> 16);
}

// ---------------- prep: fold BN into bf16 weights, pad K/N ----------------
// w1b: [256][480] bf16 (cols >=451 zero), w2b: [256][256], w3b: [64][256] (rows >=50 zero)
__global__ void prep_kernel(const float* __restrict__ w1, const float* __restrict__ b1,
                            const float* __restrict__ g1, const float* __restrict__ be1,
                            const float* __restrict__ m1, const float* __restrict__ v1,
                            const float* __restrict__ w2, const float* __restrict__ b2,
                            const float* __restrict__ g2, const float* __restrict__ be2,
                            const float* __restrict__ m2, const float* __restrict__ v2,
                            const float* __restrict__ w3, const float* __restrict__ b3,
                            u16* __restrict__ w1b, u16* __restrict__ w2b, u16* __restrict__ w3b,
                            float* __restrict__ b1p, float* __restrict__ b2p, float* __restrict__ b3p)
{
  int i = blockIdx.x * TPB + threadIdx.x;
  if (i < 256 * 480) {
    int o = i / 480;
    int k = i - o * 480;
    float s = g1[o] * rsqrtf(v1[o] + 1e-5f);
    u16 r = 0;
    if (k < 451) r = f2bf(w1[o * 451 + k] * s);
    w1b[i] = r;
  }
  if (i < 256 * 256) {
    int o = i >> 8;
    float s = g2[o] * rsqrtf(v2[o] + 1e-5f);
    w2b[i] = f2bf(w2[i] * s);
  }
  if (i < 64 * 256) {
    int o = i >> 8;
    u16 r = 0;
    if (o < 50) r = f2bf(w3[i]);
    w3b[i] = r;
  }
  if (i < 256) {
    float s1 = g1[i] * rsqrtf(v1[i] + 1e-5f);
    b1p[i] = (b1[i] - m1[i]) * s1 + be1[i];
    float s2 = g2[i] * rsqrtf(v2[i] + 1e-5f);
    b2p[i] = (b2[i] - m2[i]) * s2 + be2[i];
  }
  if (i < 64) {
    b3p[i] = (i < 50) ? b3[i] : 0.f;
  }
}

// ---------------- fused main kernel ----------------
// One block = 64 points of one batch. 4 waves; wave w owns output-channel
// stripe [w*64, w*64+64) for GEMM1/GEMM2, col-tile [w*16, w*16+16) for GEMM3.
// LDS: bufA = combined chunk (bf16, [64][264]) -> later h2; bufH = h1.
#define LDA 264

__global__ __launch_bounds__(256, 2)
void fused_kernel(const float* __restrict__ features, const float* __restrict__ centers,
                  const float* __restrict__ pc, const int* __restrict__ category,
                  const float* __restrict__ cat_embed,
                  const u16* __restrict__ w1b, const u16* __restrict__ w2b, const u16* __restrict__ w3b,
                  const float* __restrict__ b1p, const float* __restrict__ b2p, const float* __restrict__ b3p,
                  float* __restrict__ out)
{
  __shared__ u16 bufA[64 * LDA];
  __shared__ u16 bufH[64 * LDA];
  __shared__ float centl[192];
  __shared__ float pcl[192];
  __shared__ float wtl[192];
  __shared__ int   idxl[192];

  const int bx   = blockIdx.x;
  const int b    = bx >> 7;          // 128 tiles per batch
  const int n0   = (bx & 127) << 6;  // first point of tile
  const int tid  = threadIdx.x;
  const int lane = tid & 63;
  const int wv   = tid >> 6;
  const int lr   = lane & 15;          // frag row (A) / col (B,D)
  const int lk   = (lane >> 4) * 8;    // frag k offset
  const int r0   = (lane >> 4) * 4;    // D frag row offset
  const int colw = wv * 64;            // wave's output-channel base (GEMM1/2)
  const int catv = category[b];

  // ---- stage centers & pc tile ----
  if (tid < 192) centl[tid] = centers[b * 192 + tid];
  if (tid < 192) pcl[tid]   = pc[(b * 8192 + n0) * 3 + tid];
  __syncthreads();  // S1

  // ---- knn top-3 + inverse-distance weights (f32, matches ref formula) ----
  if (tid < 64) {
    float px = pcl[tid * 3 + 0], py = pcl[tid * 3 + 1], pz = pcl[tid * 3 + 2];
    float p2 = px * px + py * py + pz * pz;
    float bd0 = 3.4e38f, bd1 = 3.4e38f, bd2 = 3.4e38f;
    int bi0 = 0, bi1 = 0, bi2 = 0;
    for (int j = 0; j < 64; ++j) {
      float cx = centl[j * 3 + 0], cy = centl[j * 3 + 1], cz = centl[j * 3 + 2];
      float dotv = px * cx + py * cy + pz * cz;
      float c2 = cx * cx + cy * cy + cz * cz;
      float d2 = (p2 + c2) - 2.f * dotv;
      if (d2 < bd2) {
        if (d2 < bd1) {
          if (d2 < bd0) { bd2 = bd1; bi2 = bi1; bd1 = bd0; bi1 = bi0; bd0 = d2; bi0 = j; }
          else          { bd2 = bd1; bi2 = bi1; bd1 = d2; bi1 = j; }
        } else          { bd2 = d2; bi2 = j; }
      }
    }
    float dd0 = sqrtf(fmaxf(bd0, 1e-12f));
    float dd1 = sqrtf(fmaxf(bd1, 1e-12f));
    float dd2 = sqrtf(fmaxf(bd2, 1e-12f));
    float u0 = 1.f / (dd0 + 1e-8f);
    float u1 = 1.f / (dd1 + 1e-8f);
    float u2 = 1.f / (dd2 + 1e-8f);
    float inv = 1.f / (u0 + u1 + u2);
    wtl[tid * 3 + 0] = u0 * inv;
    wtl[tid * 3 + 1] = u1 * inv;
    wtl[tid * 3 + 2] = u2 * inv;
    idxl[tid * 3 + 0] = bi0;
    idxl[tid * 3 + 1] = bi1;
    idxl[tid * 3 + 2] = bi2;
  }
  __syncthreads();  // S2

  const float* Fb = features + b * (64 * 384);

  // ---- Phase A1: combined cols 0..255 (feature dims 0..255) -> bufA bf16 ----
  {
    int d = tid;  // 0..255
    #pragma unroll 4
    for (int p = 0; p < 64; ++p) {
      int i0 = idxl[p * 3 + 0], i1 = idxl[p * 3 + 1], i2 = idxl[p * 3 + 2];
      float q0 = wtl[p * 3 + 0], q1 = wtl[p * 3 + 1], q2 = wtl[p * 3 + 2];
      float v = q0 * Fb[i0 * 384 + d] + q1 * Fb[i1 * 384 + d] + q2 * Fb[i2 * 384 + d];
      bufA[p * LDA + d] = f2bf(v);
    }
  }
  __syncthreads();  // S3

  // ---- GEMM1 accumulators ----
  f32x4 acc[4][4];
  {
    f32x4 z = {0.f, 0.f, 0.f, 0.f};
    #pragma unroll
    for (int m = 0; m < 4; ++m)
      #pragma unroll
      for (int n = 0; n < 4; ++n) acc[m][n] = z;
  }

  // ---- GEMM1 chunk 1: K-steps over combined cols 0..255 ----
  #pragma unroll 2
  for (int ks = 0; ks < 8; ++ks) {
    int k0 = ks * 32;
    short8 av[4], bv[4];
    #pragma unroll
    for (int m = 0; m < 4; ++m)
      av[m] = *(const short8*)(&bufA[(m * 16 + lr) * LDA + k0 + lk]);
    #pragma unroll
    for (int n = 0; n < 4; ++n)
      bv[n] = *(const short8*)(w1b + (colw + n * 16 + lr) * 480 + k0 + lk);
    #pragma unroll
    for (int m = 0; m < 4; ++m)
      #pragma unroll
      for (int n = 0; n < 4; ++n)
        acc[m][n] = __builtin_amdgcn_mfma_f32_16x16x32_bf16(av[m], bv[n], acc[m][n], 0, 0, 0);
  }
  __syncthreads();  // S4 (all waves done reading chunk1 before overwrite)

  // ---- Phase A2: combined cols 256..479 -> bufA cols 0..223 ----
  // k' = col-256: [0,128) feat dims 256..383; [128,192) cat embed; [192,195) pc; [195,224) zero
  {
    int t = tid;
    if (t < 128) {
      int d = 256 + t;
      #pragma unroll 4
      for (int p = 0; p < 64; ++p) {
        int i0 = idxl[p * 3 + 0], i1 = idxl[p * 3 + 1], i2 = idxl[p * 3 + 2];
        float q0 = wtl[p * 3 + 0], q1 = wtl[p * 3 + 1], q2 = wtl[p * 3 + 2];
        float v = q0 * Fb[i0 * 384 + d] + q1 * Fb[i1 * 384 + d] + q2 * Fb[i2 * 384 + d];
        bufA[p * LDA + t] = f2bf(v);
      }
    } else if (t < 192) {
      u16 cb = f2bf(cat_embed[catv * 64 + (t - 128)]);
      #pragma unroll
      for (int p = 0; p < 64; ++p) bufA[p * LDA + t] = cb;
    } else if (t < 195) {
      #pragma unroll
      for (int p = 0; p < 64; ++p) bufA[p * LDA + t] = f2bf(pcl[p * 3 + (t - 192)]);
    } else if (t < 224) {
      #pragma unroll
      for (int p = 0; p < 64; ++p) bufA[p * LDA + t] = 0;
    }
  }
  __syncthreads();  // S5

  // ---- GEMM1 chunk 2: K-steps over combined cols 256..479 ----
  #pragma unroll 2
  for (int ks = 0; ks < 7; ++ks) {
    int k0 = ks * 32;
    short8 av[4], bv[4];
    #pragma unroll
    for (int m = 0; m < 4; ++m)
      av[m] = *(const short8*)(&bufA[(m * 16 + lr) * LDA + k0 + lk]);
    #pragma unroll
    for (int n = 0; n < 4; ++n)
      bv[n] = *(const short8*)(w1b + (colw + n * 16 + lr) * 480 + 256 + k0 + lk);
    #pragma unroll
    for (int m = 0; m < 4; ++m)
      #pragma unroll
      for (int n = 0; n < 4; ++n)
        acc[m][n] = __builtin_amdgcn_mfma_f32_16x16x32_bf16(av[m], bv[n], acc[m][n], 0, 0, 0);
  }

  // ---- epilogue 1: bias + relu -> h1 (bf16) in bufH ----
  #pragma unroll
  for (int n = 0; n < 4; ++n) {
    float bb = b1p[colw + n * 16 + lr];
    #pragma unroll
    for (int m = 0; m < 4; ++m) {
      #pragma unroll
      for (int r = 0; r < 4; ++r) {
        float v = acc[m][n][r] + bb;
        v = v > 0.f ? v : 0.f;
        bufH[(m * 16 + r0 + r) * LDA + colw + n * 16 + lr] = f2bf(v);
      }
    }
  }
  __syncthreads();  // S6

  // ---- GEMM2: h1 [64][256] x w2b -> h2 ----
  {
    f32x4 z = {0.f, 0.f, 0.f, 0.f};
    #pragma unroll
    for (int m = 0; m < 4; ++m)
      #pragma unroll
      for (int n = 0; n < 4; ++n) acc[m][n] = z;
  }
  #pragma unroll 2
  for (int ks = 0; ks < 8; ++ks) {
    int k0 = ks * 32;
    short8 av[4], bv[4];
    #pragma unroll
    for (int m = 0; m < 4; ++m)
      av[m] = *(const short8*)(&bufH[(m * 16 + lr) * LDA + k0 + lk]);
    #pragma unroll
    for (int n = 0; n < 4; ++n)
      bv[n] = *(const short8*)(w2b + (colw + n * 16 + lr) * 256 + k0 + lk);
    #pragma unroll
    for (int m = 0; m < 4; ++m)
      #pragma unroll
      for (int n = 0; n < 4; ++n)
        acc[m][n] = __builtin_amdgcn_mfma_f32_16x16x32_bf16(av[m], bv[n], acc[m][n], 0, 0, 0);
  }

  // ---- epilogue 2: bias + relu -> h2 (bf16) into bufA ----
  #pragma unroll
  for (int n = 0; n < 4; ++n) {
    float bb = b2p[colw + n * 16 + lr];
    #pragma unroll
    for (int m = 0; m < 4; ++m) {
      #pragma unroll
      for (int r = 0; r < 4; ++r) {
        float v = acc[m][n][r] + bb;
        v = v > 0.f ? v : 0.f;
        bufA[(m * 16 + r0 + r) * LDA + colw + n * 16 + lr] = f2bf(v);
      }
    }
  }
  __syncthreads();  // S7

  // ---- GEMM3: h2 [64][256] x w3b[64][256] -> logits [64][50] ----
  f32x4 acc3[4];
  {
    f32x4 z = {0.f, 0.f, 0.f, 0.f};
    #pragma unroll
    for (int m = 0; m < 4; ++m) acc3[m] = z;
  }
  #pragma unroll 2
  for (int ks = 0; ks < 8; ++ks) {
    int k0 = ks * 32;
    short8 bv = *(const short8*)(w3b + (wv * 16 + lr) * 256 + k0 + lk);
    #pragma unroll
    for (int m = 0; m < 4; ++m) {
      short8 av = *(const short8*)(&bufA[(m * 16 + lr) * LDA + k0 + lk]);
      acc3[m] = __builtin_amdgcn_mfma_f32_16x16x32_bf16(av, bv, acc3[m], 0, 0, 0);
    }
  }

  {
    int c = wv * 16 + lr;  // output channel
    if (c < 50) {
      float b3v = b3p[c];
      #pragma unroll
      for (int m = 0; m < 4; ++m) {
        #pragma unroll
        for (int r = 0; r < 4; ++r) {
          int row = n0 + m * 16 + r0 + r;
          out[(b * 8192 + row) * 50 + c] = acc3[m][r] + b3v;
        }
      }
    }
  }
}

extern "C" void kernel_launch(void* const* d_in, const int* in_sizes, int n_in,
                              void* d_out, int out_size, void* d_ws, size_t ws_size,
                              hipStream_t stream) {
  const float* features  = (const float*)d_in[0];
  const float* centers   = (const float*)d_in[1];
  const float* pc        = (const float*)d_in[2];
  const int*   category  = (const int*)d_in[3];
  const float* cat_embed = (const float*)d_in[4];
  const float* w1  = (const float*)d_in[5];
  const float* b1  = (const float*)d_in[6];
  const float* g1  = (const float*)d_in[7];
  const float* be1 = (const float*)d_in[8];
  const float* m1  = (const float*)d_in[9];
  const float* v1  = (const float*)d_in[10];
  const float* w2  = (const float*)d_in[11];
  const float* b2  = (const float*)d_in[12];
  const float* g2  = (const float*)d_in[13];
  const float* be2 = (const float*)d_in[14];
  const float* m2  = (const float*)d_in[15];
  const float* v2  = (const float*)d_in[16];
  const float* w3  = (const float*)d_in[17];
  const float* b3  = (const float*)d_in[18];
  float* out = (float*)d_out;

  char* ws = (char*)d_ws;
  u16*   w1b = (u16*)(ws);             // 256*480*2 = 245760
  u16*   w2b = (u16*)(ws + 245760);    // 256*256*2 = 131072
  u16*   w3b = (u16*)(ws + 376832);    // 64*256*2  =  32768
  float* b1p = (float*)(ws + 409600);  // 1024
  float* b2p = (float*)(ws + 410624);  // 1024
  float* b3p = (float*)(ws + 411648);  // 256

  prep_kernel<<<480, TPB, 0, stream>>>(w1, b1, g1, be1, m1, v1,
                                       w2, b2, g2, be2, m2, v2,
                                       w3, b3, w1b, w2b, w3b, b1p, b2p, b3p);

  fused_kernel<<<2048, TPB, 0, stream>>>(features, centers, pc, category, cat_embed,
                                         w1b, w2b, w3b, b1p, b2p, b3p, out);
}

// Round 2
// 227.020 us; speedup vs baseline: 1.1583x; 1.1583x over previous
//
#include <hip/hip_runtime.h>

#define TPB 256

typedef unsigned short u16;
typedef unsigned int u32;
typedef short short8 __attribute__((ext_vector_type(8)));
typedef float f32x4 __attribute__((ext_vector_type(4)));

__device__ __forceinline__ u16 f2bf(float x) {
  union { float f; u32 u; } v;
  v.f = x;
  u32 r = v.u + 0x7FFFu + ((v.u >> 16) & 1u);
  return (u16)(r >> 16);
}

// ---------------- prep: fold BN into bf16 weights, pad K/N ----------------
// w1b: [256][480] bf16 (cols >=451 zero), w2b: [256][256], w3b: [64][256] (rows >=50 zero)
__global__ void prep_kernel(const float* __restrict__ w1, const float* __restrict__ b1,
                            const float* __restrict__ g1, const float* __restrict__ be1,
                            const float* __restrict__ m1, const float* __restrict__ v1,
                            const float* __restrict__ w2, const float* __restrict__ b2,
                            const float* __restrict__ g2, const float* __restrict__ be2,
                            const float* __restrict__ m2, const float* __restrict__ v2,
                            const float* __restrict__ w3, const float* __restrict__ b3,
                            u16* __restrict__ w1b, u16* __restrict__ w2b, u16* __restrict__ w3b,
                            float* __restrict__ b1p, float* __restrict__ b2p, float* __restrict__ b3p)
{
  int i = blockIdx.x * TPB + threadIdx.x;
  if (i < 256 * 480) {
    int o = i / 480;
    int k = i - o * 480;
    float s = g1[o] * rsqrtf(v1[o] + 1e-5f);
    u16 r = 0;
    if (k < 451) r = f2bf(w1[o * 451 + k] * s);
    w1b[i] = r;
  }
  if (i < 256 * 256) {
    int o = i >> 8;
    float s = g2[o] * rsqrtf(v2[o] + 1e-5f);
    w2b[i] = f2bf(w2[i] * s);
  }
  if (i < 64 * 256) {
    int o = i >> 8;
    u16 r = 0;
    if (o < 50) r = f2bf(w3[i]);
    w3b[i] = r;
  }
  if (i < 256) {
    float s1 = g1[i] * rsqrtf(v1[i] + 1e-5f);
    b1p[i] = (b1[i] - m1[i]) * s1 + be1[i];
    float s2 = g2[i] * rsqrtf(v2[i] + 1e-5f);
    b2p[i] = (b2[i] - m2[i]) * s2 + be2[i];
  }
  if (i < 64) {
    b3p[i] = (i < 50) ? b3[i] : 0.f;
  }
}

// ---------------- fused main kernel ----------------
// One block = 64 points of one batch, 512 threads = 8 waves.
// GEMM1/GEMM2: wave w owns output-channel stripe [w*32, w*32+32).
// GEMM3: wave w -> m-tile (w&3), n-cols (w>>2)*32 + {0,16}.
// LDS bufC [64][520] u16: combined (cols 0..479) -> h1 (0..255) -> h2 (256..511).
#define LDC 520

__global__ __launch_bounds__(512, 4)
void fused_kernel(const float* __restrict__ features, const float* __restrict__ centers,
                  const float* __restrict__ pc, const int* __restrict__ category,
                  const float* __restrict__ cat_embed,
                  const u16* __restrict__ w1b, const u16* __restrict__ w2b, const u16* __restrict__ w3b,
                  const float* __restrict__ b1p, const float* __restrict__ b2p, const float* __restrict__ b3p,
                  float* __restrict__ out)
{
  __shared__ u16 bufC[64 * LDC];        // 66560 B (also aliased as knn scratch early)
  __shared__ float pcl[192];
  __shared__ float centl[192];
  __shared__ u32 wtidx[64][8];          // per point: w0,i0,w1,i1,w2,i2,pad,pad

  const int bx   = blockIdx.x;
  const int b    = bx >> 7;          // 128 tiles per batch
  const int n0   = (bx & 127) << 6;  // first point of tile
  const int tid  = threadIdx.x;
  const int lane = tid & 63;
  const int wv   = tid >> 6;           // 0..7
  const int lr   = lane & 15;          // frag row (A) / col (B,D)
  const int lk   = (lane >> 4) * 8;    // frag k offset
  const int r0   = (lane >> 4) * 4;    // D frag row offset
  const int catv = category[b];

  // knn scratch aliases bufC (dead until staging)
  float* scrd = (float*)bufC;              // [256][3] f32  (3072 B)
  int*   scri = (int*)(bufC + 1536);       // [256][3] i32  (3072 B)

  // ---- stage centers & pc tile ----
  if (tid < 192) centl[tid] = centers[b * 192 + tid];
  else if (tid < 384) pcl[tid - 192] = pc[(b * 8192 + n0) * 3 + (tid - 192)];
  __syncthreads();  // S1

  // ---- knn scan: 4 threads per point, 16 centers each ----
  if (tid < 256) {
    int p = tid >> 2, c = tid & 3;
    float px = pcl[p * 3 + 0], py = pcl[p * 3 + 1], pz = pcl[p * 3 + 2];
    float p2 = px * px + py * py + pz * pz;
    float bd0 = 3.4e38f, bd1 = 3.4e38f, bd2 = 3.4e38f;
    int bi0 = 0, bi1 = 0, bi2 = 0;
    int j0 = c * 16;
    for (int j = j0; j < j0 + 16; ++j) {
      float cx = centl[j * 3 + 0], cy = centl[j * 3 + 1], cz = centl[j * 3 + 2];
      float dotv = px * cx + py * cy + pz * cz;
      float c2 = cx * cx + cy * cy + cz * cz;
      float d2 = (p2 + c2) - 2.f * dotv;
      if (d2 < bd2) {
        if (d2 < bd1) {
          if (d2 < bd0) { bd2 = bd1; bi2 = bi1; bd1 = bd0; bi1 = bi0; bd0 = d2; bi0 = j; }
          else          { bd2 = bd1; bi2 = bi1; bd1 = d2; bi1 = j; }
        } else          { bd2 = d2; bi2 = j; }
      }
    }
    scrd[tid * 3 + 0] = bd0; scrd[tid * 3 + 1] = bd1; scrd[tid * 3 + 2] = bd2;
    scri[tid * 3 + 0] = bi0; scri[tid * 3 + 1] = bi1; scri[tid * 3 + 2] = bi2;
  }
  __syncthreads();  // S2

  // ---- knn merge + weights ----
  if (tid < 64) {
    float bd0 = 3.4e38f, bd1 = 3.4e38f, bd2 = 3.4e38f;
    int bi0 = 0, bi1 = 0, bi2 = 0;
    #pragma unroll
    for (int c = 0; c < 4; ++c) {
      int t = tid * 4 + c;
      #pragma unroll
      for (int s = 0; s < 3; ++s) {
        float d2 = scrd[t * 3 + s];
        int   j  = scri[t * 3 + s];
        if (d2 < bd2) {
          if (d2 < bd1) {
            if (d2 < bd0) { bd2 = bd1; bi2 = bi1; bd1 = bd0; bi1 = bi0; bd0 = d2; bi0 = j; }
            else          { bd2 = bd1; bi2 = bi1; bd1 = d2; bi1 = j; }
          } else          { bd2 = d2; bi2 = j; }
        }
      }
    }
    float dd0 = sqrtf(fmaxf(bd0, 1e-12f));
    float dd1 = sqrtf(fmaxf(bd1, 1e-12f));
    float dd2 = sqrtf(fmaxf(bd2, 1e-12f));
    float u0 = 1.f / (dd0 + 1e-8f);
    float u1 = 1.f / (dd1 + 1e-8f);
    float u2 = 1.f / (dd2 + 1e-8f);
    float inv = 1.f / (u0 + u1 + u2);
    wtidx[tid][0] = __float_as_uint(u0 * inv); wtidx[tid][1] = (u32)bi0;
    wtidx[tid][2] = __float_as_uint(u1 * inv); wtidx[tid][3] = (u32)bi1;
    wtidx[tid][4] = __float_as_uint(u2 * inv); wtidx[tid][5] = (u32)bi2;
  }
  __syncthreads();  // S3

  const float* Fb = features + b * (64 * 384);

  // ---- staging: all 480 combined cols as bf16 into bufC ----
  // c4 = group of 4 cols. 0..95: features; 96..111: cat; 112: pc+pad; 113..119: zeros
  {
    int c4 = tid & 127;
    int pg = tid >> 7;  // 0..3 -> points pg*16..pg*16+15
    if (c4 < 96) {
      const f32x4* F4 = (const f32x4*)Fb;
      #pragma unroll 4
      for (int pp = 0; pp < 16; ++pp) {
        int p = pg * 16 + pp;
        uint4 wa = *(const uint4*)&wtidx[p][0];
        uint2 wb = *(const uint2*)&wtidx[p][4];
        float q0 = __uint_as_float(wa.x); int i0 = (int)wa.y;
        float q1 = __uint_as_float(wa.z); int i1 = (int)wa.w;
        float q2 = __uint_as_float(wb.x); int i2 = (int)wb.y;
        f32x4 f0 = F4[i0 * 96 + c4];
        f32x4 f1 = F4[i1 * 96 + c4];
        f32x4 f2 = F4[i2 * 96 + c4];
        f32x4 v = q0 * f0 + q1 * f1 + q2 * f2;
        u32 lo = (u32)f2bf(v[0]) | ((u32)f2bf(v[1]) << 16);
        u32 hi = (u32)f2bf(v[2]) | ((u32)f2bf(v[3]) << 16);
        *(uint2*)&bufC[p * LDC + c4 * 4] = make_uint2(lo, hi);
      }
    } else if (c4 < 112) {
      const float* ce = cat_embed + catv * 64 + (c4 - 96) * 4;
      u32 lo = (u32)f2bf(ce[0]) | ((u32)f2bf(ce[1]) << 16);
      u32 hi = (u32)f2bf(ce[2]) | ((u32)f2bf(ce[3]) << 16);
      #pragma unroll
      for (int pp = 0; pp < 16; ++pp) {
        int p = pg * 16 + pp;
        *(uint2*)&bufC[p * LDC + c4 * 4] = make_uint2(lo, hi);
      }
    } else if (c4 == 112) {
      #pragma unroll
      for (int pp = 0; pp < 16; ++pp) {
        int p = pg * 16 + pp;
        u32 lo = (u32)f2bf(pcl[p * 3 + 0]) | ((u32)f2bf(pcl[p * 3 + 1]) << 16);
        u32 hi = (u32)f2bf(pcl[p * 3 + 2]);
        *(uint2*)&bufC[p * LDC + c4 * 4] = make_uint2(lo, hi);
      }
    } else if (c4 < 120) {
      #pragma unroll
      for (int pp = 0; pp < 16; ++pp) {
        int p = pg * 16 + pp;
        *(uint2*)&bufC[p * LDC + c4 * 4] = make_uint2(0u, 0u);
      }
    }
  }
  __syncthreads();  // S4

  // ---- GEMM1: combined [64][480] x w1b^T stripe -> 32 ch/wave ----
  f32x4 acc[4][2];
  {
    f32x4 z = {0.f, 0.f, 0.f, 0.f};
    #pragma unroll
    for (int m = 0; m < 4; ++m) { acc[m][0] = z; acc[m][1] = z; }
  }
  #pragma unroll 3
  for (int ks = 0; ks < 15; ++ks) {
    int k0 = ks * 32;
    short8 av[4], bv[2];
    #pragma unroll
    for (int m = 0; m < 4; ++m)
      av[m] = *(const short8*)(&bufC[(m * 16 + lr) * LDC + k0 + lk]);
    #pragma unroll
    for (int n = 0; n < 2; ++n)
      bv[n] = *(const short8*)(w1b + (wv * 32 + n * 16 + lr) * 480 + k0 + lk);
    #pragma unroll
    for (int m = 0; m < 4; ++m)
      #pragma unroll
      for (int n = 0; n < 2; ++n)
        acc[m][n] = __builtin_amdgcn_mfma_f32_16x16x32_bf16(av[m], bv[n], acc[m][n], 0, 0, 0);
  }
  __syncthreads();  // S5 (combined fully consumed)

  // ---- epilogue 1: bias+relu -> h1 into bufC cols 0..255 ----
  #pragma unroll
  for (int n = 0; n < 2; ++n) {
    float bb = b1p[wv * 32 + n * 16 + lr];
    #pragma unroll
    for (int m = 0; m < 4; ++m) {
      #pragma unroll
      for (int r = 0; r < 4; ++r) {
        float v = acc[m][n][r] + bb;
        v = v > 0.f ? v : 0.f;
        bufC[(m * 16 + r0 + r) * LDC + wv * 32 + n * 16 + lr] = f2bf(v);
      }
    }
  }
  __syncthreads();  // S6

  // ---- GEMM2: h1 [64][256] x w2b stripe -> h2 into bufC cols 256..511 ----
  {
    f32x4 z = {0.f, 0.f, 0.f, 0.f};
    #pragma unroll
    for (int m = 0; m < 4; ++m) { acc[m][0] = z; acc[m][1] = z; }
  }
  #pragma unroll 2
  for (int ks = 0; ks < 8; ++ks) {
    int k0 = ks * 32;
    short8 av[4], bv[2];
    #pragma unroll
    for (int m = 0; m < 4; ++m)
      av[m] = *(const short8*)(&bufC[(m * 16 + lr) * LDC + k0 + lk]);
    #pragma unroll
    for (int n = 0; n < 2; ++n)
      bv[n] = *(const short8*)(w2b + (wv * 32 + n * 16 + lr) * 256 + k0 + lk);
    #pragma unroll
    for (int m = 0; m < 4; ++m)
      #pragma unroll
      for (int n = 0; n < 2; ++n)
        acc[m][n] = __builtin_amdgcn_mfma_f32_16x16x32_bf16(av[m], bv[n], acc[m][n], 0, 0, 0);
  }
  __syncthreads();  // S7 (h1 fully consumed; h2 region disjoint from h1)

  // ---- epilogue 2: bias+relu -> h2 into bufC cols 256..511 ----
  #pragma unroll
  for (int n = 0; n < 2; ++n) {
    float bb = b2p[wv * 32 + n * 16 + lr];
    #pragma unroll
    for (int m = 0; m < 4; ++m) {
      #pragma unroll
      for (int r = 0; r < 4; ++r) {
        float v = acc[m][n][r] + bb;
        v = v > 0.f ? v : 0.f;
        bufC[(m * 16 + r0 + r) * LDC + 256 + wv * 32 + n * 16 + lr] = f2bf(v);
      }
    }
  }
  __syncthreads();  // S8

  // ---- GEMM3: h2 [64][256] x w3b[64][256] -> logits ----
  // wave w: m-tile (w&3), n-frags (w>>2)*32 + {0,16}
  {
    int m  = wv & 3;
    int nf = wv >> 2;
    f32x4 acc3[2];
    {
      f32x4 z = {0.f, 0.f, 0.f, 0.f};
      acc3[0] = z; acc3[1] = z;
    }
    #pragma unroll 2
    for (int ks = 0; ks < 8; ++ks) {
      int k0 = ks * 32;
      short8 av = *(const short8*)(&bufC[(m * 16 + lr) * LDC + 256 + k0 + lk]);
      #pragma unroll
      for (int j = 0; j < 2; ++j) {
        short8 bv = *(const short8*)(w3b + (nf * 32 + j * 16 + lr) * 256 + k0 + lk);
        acc3[j] = __builtin_amdgcn_mfma_f32_16x16x32_bf16(av, bv, acc3[j], 0, 0, 0);
      }
    }
    #pragma unroll
    for (int j = 0; j < 2; ++j) {
      int c = nf * 32 + j * 16 + lr;
      if (c < 50) {
        float b3v = b3p[c];
        #pragma unroll
        for (int r = 0; r < 4; ++r) {
          int row = n0 + m * 16 + r0 + r;
          out[(b * 8192 + row) * 50 + c] = acc3[j][r] + b3v;
        }
      }
    }
  }
}

extern "C" void kernel_launch(void* const* d_in, const int* in_sizes, int n_in,
                              void* d_out, int out_size, void* d_ws, size_t ws_size,
                              hipStream_t stream) {
  const float* features  = (const float*)d_in[0];
  const float* centers   = (const float*)d_in[1];
  const float* pc        = (const float*)d_in[2];
  const int*   category  = (const int*)d_in[3];
  const float* cat_embed = (const float*)d_in[4];
  const float* w1  = (const float*)d_in[5];
  const float* b1  = (const float*)d_in[6];
  const float* g1  = (const float*)d_in[7];
  const float* be1 = (const float*)d_in[8];
  const float* m1  = (const float*)d_in[9];
  const float* v1  = (const float*)d_in[10];
  const float* w2  = (const float*)d_in[11];
  const float* b2  = (const float*)d_in[12];
  const float* g2  = (const float*)d_in[13];
  const float* be2 = (const float*)d_in[14];
  const float* m2  = (const float*)d_in[15];
  const float* v2  = (const float*)d_in[16];
  const float* w3  = (const float*)d_in[17];
  const float* b3  = (const float*)d_in[18];
  float* out = (float*)d_out;

  char* ws = (char*)d_ws;
  u16*   w1b = (u16*)(ws);             // 256*480*2 = 245760
  u16*   w2b = (u16*)(ws + 245760);    // 256*256*2 = 131072
  u16*   w3b = (u16*)(ws + 376832);    // 64*256*2  =  32768
  float* b1p = (float*)(ws + 409600);  // 1024
  float* b2p = (float*)(ws + 410624);  // 1024
  float* b3p = (float*)(ws + 411648);  // 256

  prep_kernel<<<480, TPB, 0, stream>>>(w1, b1, g1, be1, m1, v1,
                                       w2, b2, g2, be2, m2, v2,
                                       w3, b3, w1b, w2b, w3b, b1p, b2p, b3p);

  fused_kernel<<<2048, 512, 0, stream>>>(features, centers, pc, category, cat_embed,
                                         w1b, w2b, w3b, b1p, b2p, b3p, out);
}

// Round 3
// 215.515 us; speedup vs baseline: 1.2201x; 1.0534x over previous
//
#include <hip/hip_runtime.h>

#define TPB 256

typedef unsigned short u16;
typedef unsigned int u32;
typedef short short8 __attribute__((ext_vector_type(8)));
typedef float f32x4 __attribute__((ext_vector_type(4)));

__device__ __forceinline__ u16 f2bf(float x) {
  union { float f; u32 u; } v;
  v.f = x;
  u32 r = v.u + 0x7FFFu + ((v.u >> 16) & 1u);
  return (u16)(r >> 16);
}

// ---------------- prep: fold BN into bf16 weights, pad K/N ----------------
__global__ void prep_kernel(const float* __restrict__ w1, const float* __restrict__ b1,
                            const float* __restrict__ g1, const float* __restrict__ be1,
                            const float* __restrict__ m1, const float* __restrict__ v1,
                            const float* __restrict__ w2, const float* __restrict__ b2,
                            const float* __restrict__ g2, const float* __restrict__ be2,
                            const float* __restrict__ m2, const float* __restrict__ v2,
                            const float* __restrict__ w3, const float* __restrict__ b3,
                            u16* __restrict__ w1b, u16* __restrict__ w2b, u16* __restrict__ w3b,
                            float* __restrict__ b1p, float* __restrict__ b2p, float* __restrict__ b3p)
{
  int i = blockIdx.x * TPB + threadIdx.x;
  if (i < 256 * 480) {
    int o = i / 480;
    int k = i - o * 480;
    float s = g1[o] * rsqrtf(v1[o] + 1e-5f);
    u16 r = 0;
    if (k < 451) r = f2bf(w1[o * 451 + k] * s);
    w1b[i] = r;
  }
  if (i < 256 * 256) {
    int o = i >> 8;
    float s = g2[o] * rsqrtf(v2[o] + 1e-5f);
    w2b[i] = f2bf(w2[i] * s);
  }
  if (i < 64 * 256) {
    int o = i >> 8;
    u16 r = 0;
    if (o < 50) r = f2bf(w3[i]);
    w3b[i] = r;
  }
  if (i < 256) {
    float s1 = g1[i] * rsqrtf(v1[i] + 1e-5f);
    b1p[i] = (b1[i] - m1[i]) * s1 + be1[i];
    float s2 = g2[i] * rsqrtf(v2[i] + 1e-5f);
    b2p[i] = (b2[i] - m2[i]) * s2 + be2[i];
  }
  if (i < 64) {
    b3p[i] = (i < 50) ? b3[i] : 0.f;
  }
}

// ---------------- transpose features -> FT bf16 [b][384 dims][64 centers] ----------------
__global__ void trans_kernel(const float* __restrict__ features, u16* __restrict__ FT) {
  int b  = blockIdx.x / 6;
  int d0 = (blockIdx.x % 6) * 64;
  const float* F = features + b * 24576;
  u32* FTb = (u32*)(FT + b * 24576);
  int tid = threadIdx.x;
  #pragma unroll
  for (int it = 0; it < 8; ++it) {
    int i = tid + it * 256;           // i < 64*32
    int d = d0 + (i >> 5);
    int c2 = i & 31;
    float lo = F[(2 * c2 + 0) * 384 + d];
    float hi = F[(2 * c2 + 1) * 384 + d];
    FTb[d * 32 + c2] = (u32)f2bf(lo) | ((u32)f2bf(hi) << 16);
  }
}

// ---------------- fused main kernel ----------------
// One block = 64 points of one batch, 512 threads = 8 waves.
// Stage 0: knn -> sparse P[64x64] in LDS.  Stage 1: PF = P x F^T (MFMA) -> bufC cols 0..383,
// cat/pc/zero -> cols 384..479.  GEMM1 (K=480) -> h1 cols 0..255.  GEMM2 -> h2 cols 0..255.
// GEMM3 -> out. Weights preloaded into regs across barriers.
#define LDC 488
#define LDP 72

__global__ __launch_bounds__(512, 4)
void fused_kernel(const float* __restrict__ centers, const float* __restrict__ pc,
                  const int* __restrict__ category, const float* __restrict__ cat_embed,
                  const u16* __restrict__ FT,
                  const u16* __restrict__ w1b, const u16* __restrict__ w2b, const u16* __restrict__ w3b,
                  const float* __restrict__ b1p, const float* __restrict__ b2p, const float* __restrict__ b3p,
                  float* __restrict__ out)
{
  __shared__ u16 bufC[64 * LDC];   // 62464 B
  __shared__ u16 Pm[64 * LDP];     //  9216 B
  __shared__ float pcl[192];
  __shared__ float centl[192];

  const int bx   = blockIdx.x;
  const int b    = bx >> 7;
  const int n0   = (bx & 127) << 6;
  const int tid  = threadIdx.x;
  const int lane = tid & 63;
  const int wv   = tid >> 6;           // 0..7
  const int lr   = lane & 15;
  const int lk   = (lane >> 4) * 8;
  const int r0   = (lane >> 4) * 4;
  const int catv = category[b];

  // knn scratch aliases bufC (dead before PF writes)
  float* scrd = (float*)bufC;              // [256][3] f32
  int*   scri = (int*)(bufC + 1536);       // [256][3] i32

  // ---- zero P + stage centers/pc ----
  {
    u32* Pw = (u32*)Pm;
    #pragma unroll
    for (int i = 0; i < 4; ++i) Pw[tid + 512 * i] = 0;
    if (tid < 256) Pw[2048 + tid] = 0;
  }
  if (tid < 192) centl[tid] = centers[b * 192 + tid];
  else if (tid < 384) pcl[tid - 192] = pc[(b * 8192 + n0) * 3 + (tid - 192)];
  __syncthreads();  // S1

  // ---- knn scan: 4 threads per point, 16 centers each ----
  if (tid < 256) {
    int p = tid >> 2, c = tid & 3;
    float px = pcl[p * 3 + 0], py = pcl[p * 3 + 1], pz = pcl[p * 3 + 2];
    float p2 = px * px + py * py + pz * pz;
    float bd0 = 3.4e38f, bd1 = 3.4e38f, bd2 = 3.4e38f;
    int bi0 = 0, bi1 = 0, bi2 = 0;
    int j0 = c * 16;
    for (int j = j0; j < j0 + 16; ++j) {
      float cx = centl[j * 3 + 0], cy = centl[j * 3 + 1], cz = centl[j * 3 + 2];
      float dotv = px * cx + py * cy + pz * cz;
      float c2 = cx * cx + cy * cy + cz * cz;
      float d2 = (p2 + c2) - 2.f * dotv;
      if (d2 < bd2) {
        if (d2 < bd1) {
          if (d2 < bd0) { bd2 = bd1; bi2 = bi1; bd1 = bd0; bi1 = bi0; bd0 = d2; bi0 = j; }
          else          { bd2 = bd1; bi2 = bi1; bd1 = d2; bi1 = j; }
        } else          { bd2 = d2; bi2 = j; }
      }
    }
    scrd[tid * 3 + 0] = bd0; scrd[tid * 3 + 1] = bd1; scrd[tid * 3 + 2] = bd2;
    scri[tid * 3 + 0] = bi0; scri[tid * 3 + 1] = bi1; scri[tid * 3 + 2] = bi2;
  }
  __syncthreads();  // S2

  // ---- knn merge + scatter weights into P ----
  if (tid < 64) {
    float bd0 = 3.4e38f, bd1 = 3.4e38f, bd2 = 3.4e38f;
    int bi0 = 0, bi1 = 0, bi2 = 0;
    #pragma unroll
    for (int c = 0; c < 4; ++c) {
      int t = tid * 4 + c;
      #pragma unroll
      for (int s = 0; s < 3; ++s) {
        float d2 = scrd[t * 3 + s];
        int   j  = scri[t * 3 + s];
        if (d2 < bd2) {
          if (d2 < bd1) {
            if (d2 < bd0) { bd2 = bd1; bi2 = bi1; bd1 = bd0; bi1 = bi0; bd0 = d2; bi0 = j; }
            else          { bd2 = bd1; bi2 = bi1; bd1 = d2; bi1 = j; }
          } else          { bd2 = d2; bi2 = j; }
        }
      }
    }
    float dd0 = sqrtf(fmaxf(bd0, 1e-12f));
    float dd1 = sqrtf(fmaxf(bd1, 1e-12f));
    float dd2 = sqrtf(fmaxf(bd2, 1e-12f));
    float u0 = 1.f / (dd0 + 1e-8f);
    float u1 = 1.f / (dd1 + 1e-8f);
    float u2 = 1.f / (dd2 + 1e-8f);
    float inv = 1.f / (u0 + u1 + u2);
    Pm[tid * LDP + bi0] = f2bf(u0 * inv);
    Pm[tid * LDP + bi1] = f2bf(u1 * inv);
    Pm[tid * LDP + bi2] = f2bf(u2 * inv);
  }
  __syncthreads();  // S3

  const u16* FTb = FT + b * 24576;

  // ---- PF phase: issue FT loads, stage cat/pc/zero cols, P x F^T MFMA ----
  short8 ftv[3][2];
  #pragma unroll
  for (int nf = 0; nf < 3; ++nf)
    #pragma unroll
    for (int ks = 0; ks < 2; ++ks)
      ftv[nf][ks] = *(const short8*)(FTb + (wv * 48 + nf * 16 + lr) * 64 + ks * 32 + lk);

  #pragma unroll
  for (int i = 0; i < 3; ++i) {
    int idx = tid + 512 * i;
    int p = idx & 63;
    int g = idx >> 6;  // 0..23
    u32 lo, hi;
    if (g < 16) {
      f32x4 ce = *(const f32x4*)(cat_embed + catv * 64 + g * 4);
      lo = (u32)f2bf(ce[0]) | ((u32)f2bf(ce[1]) << 16);
      hi = (u32)f2bf(ce[2]) | ((u32)f2bf(ce[3]) << 16);
    } else if (g == 16) {
      lo = (u32)f2bf(pcl[p * 3 + 0]) | ((u32)f2bf(pcl[p * 3 + 1]) << 16);
      hi = (u32)f2bf(pcl[p * 3 + 2]);
    } else {
      lo = 0u; hi = 0u;
    }
    *(uint2*)&bufC[p * LDC + 384 + g * 4] = make_uint2(lo, hi);
  }

  {
    f32x4 pfa[4][3];
    f32x4 z = {0.f, 0.f, 0.f, 0.f};
    #pragma unroll
    for (int m = 0; m < 4; ++m)
      #pragma unroll
      for (int nf = 0; nf < 3; ++nf) pfa[m][nf] = z;
    #pragma unroll
    for (int ks = 0; ks < 2; ++ks) {
      short8 av[4];
      #pragma unroll
      for (int m = 0; m < 4; ++m)
        av[m] = *(const short8*)(&Pm[(m * 16 + lr) * LDP + ks * 32 + lk]);
      #pragma unroll
      for (int m = 0; m < 4; ++m)
        #pragma unroll
        for (int nf = 0; nf < 3; ++nf)
          pfa[m][nf] = __builtin_amdgcn_mfma_f32_16x16x32_bf16(av[m], ftv[nf][ks], pfa[m][nf], 0, 0, 0);
    }
    // PF epilogue -> bufC cols 0..383
    #pragma unroll
    for (int m = 0; m < 4; ++m)
      #pragma unroll
      for (int nf = 0; nf < 3; ++nf)
        #pragma unroll
        for (int r = 0; r < 4; ++r)
          bufC[(m * 16 + r0 + r) * LDC + wv * 48 + nf * 16 + lr] = f2bf(pfa[m][nf][r]);
  }

  // ---- preload first 6 k-steps of w1 (stay in flight across S4) ----
  short8 w1f[6][2];
  #pragma unroll
  for (int ks = 0; ks < 6; ++ks)
    #pragma unroll
    for (int n = 0; n < 2; ++n)
      w1f[ks][n] = *(const short8*)(w1b + (wv * 32 + n * 16 + lr) * 480 + ks * 32 + lk);

  f32x4 acc[4][2];
  {
    f32x4 z = {0.f, 0.f, 0.f, 0.f};
    #pragma unroll
    for (int m = 0; m < 4; ++m) { acc[m][0] = z; acc[m][1] = z; }
  }
  __syncthreads();  // S4

  // ---- GEMM1: combined [64][480] -> 32 ch/wave ----
  #pragma unroll
  for (int ks = 0; ks < 6; ++ks) {
    short8 av[4];
    #pragma unroll
    for (int m = 0; m < 4; ++m)
      av[m] = *(const short8*)(&bufC[(m * 16 + lr) * LDC + ks * 32 + lk]);
    #pragma unroll
    for (int m = 0; m < 4; ++m)
      #pragma unroll
      for (int n = 0; n < 2; ++n)
        acc[m][n] = __builtin_amdgcn_mfma_f32_16x16x32_bf16(av[m], w1f[ks][n], acc[m][n], 0, 0, 0);
  }
  #pragma unroll
  for (int ks = 6; ks < 15; ++ks) {
    short8 av[4], bv[2];
    #pragma unroll
    for (int n = 0; n < 2; ++n)
      bv[n] = *(const short8*)(w1b + (wv * 32 + n * 16 + lr) * 480 + ks * 32 + lk);
    #pragma unroll
    for (int m = 0; m < 4; ++m)
      av[m] = *(const short8*)(&bufC[(m * 16 + lr) * LDC + ks * 32 + lk]);
    #pragma unroll
    for (int m = 0; m < 4; ++m)
      #pragma unroll
      for (int n = 0; n < 2; ++n)
        acc[m][n] = __builtin_amdgcn_mfma_f32_16x16x32_bf16(av[m], bv[n], acc[m][n], 0, 0, 0);
  }
  __syncthreads();  // S5

  // ---- epilogue 1 -> h1 into cols 0..255 ----
  #pragma unroll
  for (int n = 0; n < 2; ++n) {
    float bb = b1p[wv * 32 + n * 16 + lr];
    #pragma unroll
    for (int m = 0; m < 4; ++m)
      #pragma unroll
      for (int r = 0; r < 4; ++r) {
        float v = acc[m][n][r] + bb;
        v = v > 0.f ? v : 0.f;
        bufC[(m * 16 + r0 + r) * LDC + wv * 32 + n * 16 + lr] = f2bf(v);
      }
  }

  // ---- preload first 6 k-steps of w2 (in flight across S6) ----
  short8 w2f[6][2];
  #pragma unroll
  for (int ks = 0; ks < 6; ++ks)
    #pragma unroll
    for (int n = 0; n < 2; ++n)
      w2f[ks][n] = *(const short8*)(w2b + (wv * 32 + n * 16 + lr) * 256 + ks * 32 + lk);
  {
    f32x4 z = {0.f, 0.f, 0.f, 0.f};
    #pragma unroll
    for (int m = 0; m < 4; ++m) { acc[m][0] = z; acc[m][1] = z; }
  }
  __syncthreads();  // S6

  // ---- GEMM2: h1 x w2 -> h2 ----
  #pragma unroll
  for (int ks = 0; ks < 6; ++ks) {
    short8 av[4];
    #pragma unroll
    for (int m = 0; m < 4; ++m)
      av[m] = *(const short8*)(&bufC[(m * 16 + lr) * LDC + ks * 32 + lk]);
    #pragma unroll
    for (int m = 0; m < 4; ++m)
      #pragma unroll
      for (int n = 0; n < 2; ++n)
        acc[m][n] = __builtin_amdgcn_mfma_f32_16x16x32_bf16(av[m], w2f[ks][n], acc[m][n], 0, 0, 0);
  }
  #pragma unroll
  for (int ks = 6; ks < 8; ++ks) {
    short8 av[4], bv[2];
    #pragma unroll
    for (int n = 0; n < 2; ++n)
      bv[n] = *(const short8*)(w2b + (wv * 32 + n * 16 + lr) * 256 + ks * 32 + lk);
    #pragma unroll
    for (int m = 0; m < 4; ++m)
      av[m] = *(const short8*)(&bufC[(m * 16 + lr) * LDC + ks * 32 + lk]);
    #pragma unroll
    for (int m = 0; m < 4; ++m)
      #pragma unroll
      for (int n = 0; n < 2; ++n)
        acc[m][n] = __builtin_amdgcn_mfma_f32_16x16x32_bf16(av[m], bv[n], acc[m][n], 0, 0, 0);
  }
  __syncthreads();  // S7

  // ---- epilogue 2 -> h2 into cols 0..255 (overwrites h1) ----
  #pragma unroll
  for (int n = 0; n < 2; ++n) {
    float bb = b2p[wv * 32 + n * 16 + lr];
    #pragma unroll
    for (int m = 0; m < 4; ++m)
      #pragma unroll
      for (int r = 0; r < 4; ++r) {
        float v = acc[m][n][r] + bb;
        v = v > 0.f ? v : 0.f;
        bufC[(m * 16 + r0 + r) * LDC + wv * 32 + n * 16 + lr] = f2bf(v);
      }
  }

  // ---- preload all w3 frags for this wave (in flight across S8) ----
  const int m3  = wv & 3;
  const int nfg = wv >> 2;
  short8 w3f[8][2];
  #pragma unroll
  for (int ks = 0; ks < 8; ++ks)
    #pragma unroll
    for (int j = 0; j < 2; ++j)
      w3f[ks][j] = *(const short8*)(w3b + (nfg * 32 + j * 16 + lr) * 256 + ks * 32 + lk);
  __syncthreads();  // S8

  // ---- GEMM3: h2 x w3 -> logits ----
  {
    f32x4 acc3[2];
    f32x4 z = {0.f, 0.f, 0.f, 0.f};
    acc3[0] = z; acc3[1] = z;
    #pragma unroll
    for (int ks = 0; ks < 8; ++ks) {
      short8 av = *(const short8*)(&bufC[(m3 * 16 + lr) * LDC + ks * 32 + lk]);
      #pragma unroll
      for (int j = 0; j < 2; ++j)
        acc3[j] = __builtin_amdgcn_mfma_f32_16x16x32_bf16(av, w3f[ks][j], acc3[j], 0, 0, 0);
    }
    #pragma unroll
    for (int j = 0; j < 2; ++j) {
      int c = nfg * 32 + j * 16 + lr;
      if (c < 50) {
        float b3v = b3p[c];
        #pragma unroll
        for (int r = 0; r < 4; ++r) {
          int row = n0 + m3 * 16 + r0 + r;
          out[(b * 8192 + row) * 50 + c] = acc3[j][r] + b3v;
        }
      }
    }
  }
}

extern "C" void kernel_launch(void* const* d_in, const int* in_sizes, int n_in,
                              void* d_out, int out_size, void* d_ws, size_t ws_size,
                              hipStream_t stream) {
  const float* features  = (const float*)d_in[0];
  const float* centers   = (const float*)d_in[1];
  const float* pc        = (const float*)d_in[2];
  const int*   category  = (const int*)d_in[3];
  const float* cat_embed = (const float*)d_in[4];
  const float* w1  = (const float*)d_in[5];
  const float* b1  = (const float*)d_in[6];
  const float* g1  = (const float*)d_in[7];
  const float* be1 = (const float*)d_in[8];
  const float* m1  = (const float*)d_in[9];
  const float* v1  = (const float*)d_in[10];
  const float* w2  = (const float*)d_in[11];
  const float* b2  = (const float*)d_in[12];
  const float* g2  = (const float*)d_in[13];
  const float* be2 = (const float*)d_in[14];
  const float* m2  = (const float*)d_in[15];
  const float* v2  = (const float*)d_in[16];
  const float* w3  = (const float*)d_in[17];
  const float* b3  = (const float*)d_in[18];
  float* out = (float*)d_out;

  char* ws = (char*)d_ws;
  u16*   w1b = (u16*)(ws);             // 245760 B
  u16*   w2b = (u16*)(ws + 245760);    // 131072 B
  u16*   w3b = (u16*)(ws + 376832);    //  32768 B
  float* b1p = (float*)(ws + 409600);  //   1024 B
  float* b2p = (float*)(ws + 410624);  //   1024 B
  float* b3p = (float*)(ws + 411648);  //    256 B
  u16*   FT  = (u16*)(ws + 413696);    // 786432 B -> ends ~1.2 MB

  prep_kernel<<<480, TPB, 0, stream>>>(w1, b1, g1, be1, m1, v1,
                                       w2, b2, g2, be2, m2, v2,
                                       w3, b3, w1b, w2b, w3b, b1p, b2p, b3p);
  trans_kernel<<<96, TPB, 0, stream>>>(features, FT);

  fused_kernel<<<2048, 512, 0, stream>>>(centers, pc, category, cat_embed, FT,
                                         w1b, w2b, w3b, b1p, b2p, b3p, out);
}

// Round 4
// 168.453 us; speedup vs baseline: 1.5610x; 1.2794x over previous
//
#include <hip/hip_runtime.h>

#define TPB 256

typedef unsigned short u16;
typedef unsigned int u32;
typedef short short8 __attribute__((ext_vector_type(8)));
typedef float f32x4 __attribute__((ext_vector_type(4)));

#define KEEP(x) asm volatile("" :: "v"(x))

__device__ __forceinline__ u16 f2bf(float x) {
  union { float f; u32 u; } v;
  v.f = x;
  u32 r = v.u + 0x7FFFu + ((v.u >> 16) & 1u);
  return (u16)(r >> 16);
}

__device__ __forceinline__ float bf2f(u16 x) {
  union { u32 u; float f; } v;
  v.u = ((u32)x) << 16;
  return v.f;
}

// ---------------- prep: fold BN into bf16 weights, pad K/N ----------------
// w1b: [256][480] bf16 (cols>=451 zero), w2b: [256][256], w3b: [64][256] (rows>=50 zero)
__global__ void prep_kernel(const float* __restrict__ w1, const float* __restrict__ b1,
                            const float* __restrict__ g1, const float* __restrict__ be1,
                            const float* __restrict__ m1, const float* __restrict__ v1,
                            const float* __restrict__ w2, const float* __restrict__ b2,
                            const float* __restrict__ g2, const float* __restrict__ be2,
                            const float* __restrict__ m2, const float* __restrict__ v2,
                            const float* __restrict__ w3, const float* __restrict__ b3,
                            u16* __restrict__ w1b, u16* __restrict__ w2b, u16* __restrict__ w3b,
                            float* __restrict__ b1p, float* __restrict__ b2p, float* __restrict__ b3p)
{
  int i = blockIdx.x * TPB + threadIdx.x;
  if (i < 256 * 480) {
    int o = i / 480;
    int k = i - o * 480;
    float s = g1[o] * rsqrtf(v1[o] + 1e-5f);
    u16 r = 0;
    if (k < 451) r = f2bf(w1[o * 451 + k] * s);
    w1b[i] = r;
  }
  if (i < 256 * 256) {
    int o = i >> 8;
    float s = g2[o] * rsqrtf(v2[o] + 1e-5f);
    w2b[i] = f2bf(w2[i] * s);
  }
  if (i < 64 * 256) {
    int o = i >> 8;
    u16 r = 0;
    if (o < 50) r = f2bf(w3[i]);
    w3b[i] = r;
  }
  if (i < 256) {
    float s1 = g1[i] * rsqrtf(v1[i] + 1e-5f);
    b1p[i] = (b1[i] - m1[i]) * s1 + be1[i];
    float s2 = g2[i] * rsqrtf(v2[i] + 1e-5f);
    b2p[i] = (b2[i] - m2[i]) * s2 + be2[i];
  }
  if (i < 64) {
    b3p[i] = (i < 50) ? b3[i] : 0.f;
  }
}

// ---------------- gcalc: G[b][o][k] (k<64: sum_d F[b][k][d]*w1s[o][d]; 64..66: pc-w; else 0)
// + bias1[b][o] = b1p[o] + sum_j w1s[o][384+j]*cat_embed[cat[b]][j]
// One block per (batch, o-half). 512 threads = 8 waves, 16 ch/wave, M=64 centers.
__global__ __launch_bounds__(512, 2)
void gcalc_kernel(const float* __restrict__ features, const int* __restrict__ category,
                  const float* __restrict__ cat_embed, const u16* __restrict__ w1b,
                  const float* __restrict__ b1p,
                  u16* __restrict__ G, float* __restrict__ bias1)
{
  __shared__ u16 Fs[64 * 392];   // 50176 B
  const int b    = blockIdx.x >> 1;
  const int och0 = (blockIdx.x & 1) * 128;
  const int tid  = threadIdx.x;
  const int lane = tid & 63;
  const int wv   = tid >> 6;
  const int lr   = lane & 15;
  const int lk   = (lane >> 4) * 8;
  const int r0   = (lane >> 4) * 4;
  const int catv = category[b];

  // stage F as bf16 [64][392]
  const f32x4* F4 = (const f32x4*)(features + b * 24576);
  #pragma unroll
  for (int it = 0; it < 12; ++it) {
    int idx = tid + 512 * it;          // < 6144
    int c = idx / 96;
    int d4 = idx - c * 96;
    f32x4 v = F4[c * 96 + d4];
    u32 lo = (u32)f2bf(v[0]) | ((u32)f2bf(v[1]) << 16);
    u32 hi = (u32)f2bf(v[2]) | ((u32)f2bf(v[3]) << 16);
    *(uint2*)&Fs[c * 392 + d4 * 4] = make_uint2(lo, hi);
  }

  // bias1 + G tail rows (pc cols 64..66, zeros 67..95)
  if (tid < 128) {
    int o = och0 + tid;
    float acc = b1p[o];
    const u16* wr = w1b + o * 480 + 384;
    const float* ce = cat_embed + catv * 64;
    #pragma unroll 8
    for (int j = 0; j < 64; ++j) acc += bf2f(wr[j]) * ce[j];
    bias1[b * 256 + o] = acc;
    u16* Go = G + (b * 256 + o) * 96;
    Go[64] = wr[64]; Go[65] = wr[65]; Go[66] = wr[66];
    #pragma unroll
    for (int k = 67; k < 96; ++k) Go[k] = 0;
  }
  __syncthreads();

  // GEMM: Fs [64][384] x w1b-stripe -> G[o][center]
  const int ch = och0 + wv * 16 + lr;
  f32x4 acc[4];
  {
    f32x4 z = {0.f, 0.f, 0.f, 0.f};
    #pragma unroll
    for (int m = 0; m < 4; ++m) acc[m] = z;
  }
  #pragma unroll
  for (int ks = 0; ks < 12; ++ks) {
    short8 bv = *(const short8*)(w1b + ch * 480 + ks * 32 + lk);
    #pragma unroll
    for (int m = 0; m < 4; ++m) {
      short8 av = *(const short8*)(&Fs[(m * 16 + lr) * 392 + ks * 32 + lk]);
      acc[m] = __builtin_amdgcn_mfma_f32_16x16x32_bf16(av, bv, acc[m], 0, 0, 0);
    }
  }
  #pragma unroll
  for (int m = 0; m < 4; ++m)
    #pragma unroll
    for (int r = 0; r < 4; ++r)
      G[(b * 256 + ch) * 96 + m * 16 + r0 + r] = f2bf(acc[m][r]);
}

// ---------------- fused main kernel ----------------
// One block = 128 points, 512 threads = 8 waves.
// knn -> P_ext[128][96] (interp wts cols 0..63, pc 64..66, 0 pad) in LDS.
// GEMM1: P_ext x G[b] (K=96) -> h1[128][256] (+bias1, relu).
// GEMM2: h1 x w2b -> h2 (+b2p, relu, in place). GEMM3: h2 x w3b -> out.
// h-buffer accesses XOR-swizzled: col ^= ((row>>2)&7)<<3 (u16), g ^= (row>>2)&7 (b128).
#define LDP 104
#define LDH 264

__global__ __launch_bounds__(512, 4)
void fused_kernel(const float* __restrict__ centers, const float* __restrict__ pc,
                  const u16* __restrict__ G, const float* __restrict__ bias1,
                  const u16* __restrict__ w2b, const u16* __restrict__ w3b,
                  const float* __restrict__ b2p, const float* __restrict__ b3p,
                  float* __restrict__ out)
{
  __shared__ u16 hbuf[128 * LDH];   // 67584 B; aliases: P_ext @0 (26624), scr @32768
  __shared__ float centl[192];
  __shared__ float pcl[384];

  const int bx   = blockIdx.x;
  const int b    = bx >> 6;           // 64 tiles per batch
  const int n0   = (bx & 63) << 7;    // first point
  const int tid  = threadIdx.x;
  const int lane = tid & 63;
  const int wv   = tid >> 6;          // 0..7
  const int lr   = lane & 15;
  const int lk   = (lane >> 4) * 8;
  const int r0   = (lane >> 4) * 4;

  u16*   Pm   = hbuf;                              // [128][LDP]
  float* scrd = (float*)((char*)hbuf + 32768);     // [512][3]
  int*   scri = (int*)((char*)hbuf + 40960);       // [512][3]

  // ---- preload this wave's G fragments (complete during knn) ----
  short8 bvG[3][2];
  #pragma unroll
  for (int ks = 0; ks < 3; ++ks)
    #pragma unroll
    for (int n = 0; n < 2; ++n)
      bvG[ks][n] = *(const short8*)(G + (b * 256 + wv * 32 + n * 16 + lr) * 96 + ks * 32 + lk);

  // ---- zero P_ext + stage centers/pc ----
  {
    u32* Pw = (u32*)Pm;
    #pragma unroll
    for (int i = 0; i < 13; ++i) Pw[tid + 512 * i] = 0;
  }
  if (tid < 192) centl[tid] = centers[b * 192 + tid];
  if (tid < 384) pcl[tid] = pc[(b * 8192 + n0) * 3 + tid];
  __syncthreads();  // S1

  // ---- knn scan: 4 threads/point, 16 centers each ----
  {
    int p = tid >> 2, c = tid & 3;
    float px = pcl[p * 3 + 0], py = pcl[p * 3 + 1], pz = pcl[p * 3 + 2];
    float p2 = px * px + py * py + pz * pz;
    float bd0 = 3.4e38f, bd1 = 3.4e38f, bd2 = 3.4e38f;
    int bi0 = 0, bi1 = 0, bi2 = 0;
    int j0 = c * 16;
    for (int j = j0; j < j0 + 16; ++j) {
      float cx = centl[j * 3 + 0], cy = centl[j * 3 + 1], cz = centl[j * 3 + 2];
      float dotv = px * cx + py * cy + pz * cz;
      float c2 = cx * cx + cy * cy + cz * cz;
      float d2 = (p2 + c2) - 2.f * dotv;
      if (d2 < bd2) {
        if (d2 < bd1) {
          if (d2 < bd0) { bd2 = bd1; bi2 = bi1; bd1 = bd0; bi1 = bi0; bd0 = d2; bi0 = j; }
          else          { bd2 = bd1; bi2 = bi1; bd1 = d2; bi1 = j; }
        } else          { bd2 = d2; bi2 = j; }
      }
    }
    scrd[tid * 3 + 0] = bd0; scrd[tid * 3 + 1] = bd1; scrd[tid * 3 + 2] = bd2;
    scri[tid * 3 + 0] = bi0; scri[tid * 3 + 1] = bi1; scri[tid * 3 + 2] = bi2;
  }
  __syncthreads();  // S2

  // ---- merge + scatter interp weights & pc into P_ext ----
  if (tid < 128) {
    float bd0 = 3.4e38f, bd1 = 3.4e38f, bd2 = 3.4e38f;
    int bi0 = 0, bi1 = 0, bi2 = 0;
    #pragma unroll
    for (int c = 0; c < 4; ++c) {
      int t = tid * 4 + c;
      #pragma unroll
      for (int s = 0; s < 3; ++s) {
        float d2 = scrd[t * 3 + s];
        int   j  = scri[t * 3 + s];
        if (d2 < bd2) {
          if (d2 < bd1) {
            if (d2 < bd0) { bd2 = bd1; bi2 = bi1; bd1 = bd0; bi1 = bi0; bd0 = d2; bi0 = j; }
            else          { bd2 = bd1; bi2 = bi1; bd1 = d2; bi1 = j; }
          } else          { bd2 = d2; bi2 = j; }
        }
      }
    }
    float dd0 = sqrtf(fmaxf(bd0, 1e-12f));
    float dd1 = sqrtf(fmaxf(bd1, 1e-12f));
    float dd2 = sqrtf(fmaxf(bd2, 1e-12f));
    float u0 = 1.f / (dd0 + 1e-8f);
    float u1 = 1.f / (dd1 + 1e-8f);
    float u2 = 1.f / (dd2 + 1e-8f);
    float inv = 1.f / (u0 + u1 + u2);
    u16* Pr = Pm + tid * LDP;
    Pr[bi0] = f2bf(u0 * inv);
    Pr[bi1] = f2bf(u1 * inv);
    Pr[bi2] = f2bf(u2 * inv);
    Pr[64] = f2bf(pcl[tid * 3 + 0]);
    Pr[65] = f2bf(pcl[tid * 3 + 1]);
    Pr[66] = f2bf(pcl[tid * 3 + 2]);
  }
  KEEP(bvG[0][0]); KEEP(bvG[0][1]); KEEP(bvG[1][0]);
  KEEP(bvG[1][1]); KEEP(bvG[2][0]); KEEP(bvG[2][1]);
  __syncthreads();  // S3

  // ---- GEMM1: P_ext [128][96] x G-stripe -> 32 ch/wave ----
  f32x4 acc[8][2];
  {
    f32x4 z = {0.f, 0.f, 0.f, 0.f};
    #pragma unroll
    for (int m = 0; m < 8; ++m) { acc[m][0] = z; acc[m][1] = z; }
  }
  #pragma unroll
  for (int ks = 0; ks < 3; ++ks) {
    short8 av[8];
    #pragma unroll
    for (int m = 0; m < 8; ++m)
      av[m] = *(const short8*)(&Pm[(m * 16 + lr) * LDP + ks * 32 + lk]);
    #pragma unroll
    for (int m = 0; m < 8; ++m)
      #pragma unroll
      for (int n = 0; n < 2; ++n)
        acc[m][n] = __builtin_amdgcn_mfma_f32_16x16x32_bf16(av[m], bvG[ks][n], acc[m][n], 0, 0, 0);
  }
  __syncthreads();  // S4 (P_ext dead; h1 may overwrite)

  // ---- epilogue 1: bias1 + relu -> h1 (swizzled) ----
  #pragma unroll
  for (int n = 0; n < 2; ++n) {
    float bb = bias1[b * 256 + wv * 32 + n * 16 + lr];
    #pragma unroll
    for (int m = 0; m < 8; ++m)
      #pragma unroll
      for (int r = 0; r < 4; ++r) {
        float v = acc[m][n][r] + bb;
        v = v > 0.f ? v : 0.f;
        int row = m * 16 + r0 + r;
        int col = (wv * 32 + n * 16 + lr) ^ (((row >> 2) & 7) << 3);
        hbuf[row * LDH + col] = f2bf(v);
      }
  }
  __syncthreads();  // S5

  // ---- GEMM2: h1 [128][256] x w2b-stripe -> h2 ----
  {
    f32x4 z = {0.f, 0.f, 0.f, 0.f};
    #pragma unroll
    for (int m = 0; m < 8; ++m) { acc[m][0] = z; acc[m][1] = z; }
  }
  #pragma unroll
  for (int ks = 0; ks < 8; ++ks) {
    short8 bv[2];
    #pragma unroll
    for (int n = 0; n < 2; ++n)
      bv[n] = *(const short8*)(w2b + (wv * 32 + n * 16 + lr) * 256 + ks * 32 + lk);
    short8 av[8];
    #pragma unroll
    for (int m = 0; m < 8; ++m) {
      int row = m * 16 + lr;
      int g = (ks * 4 + (lane >> 4)) ^ ((row >> 2) & 7);
      av[m] = *(const short8*)(&hbuf[row * LDH + g * 8]);
    }
    #pragma unroll
    for (int m = 0; m < 8; ++m)
      #pragma unroll
      for (int n = 0; n < 2; ++n)
        acc[m][n] = __builtin_amdgcn_mfma_f32_16x16x32_bf16(av[m], bv[n], acc[m][n], 0, 0, 0);
  }
  __syncthreads();  // S6

  // ---- epilogue 2: b2p + relu -> h2 in place (swizzled) ----
  #pragma unroll
  for (int n = 0; n < 2; ++n) {
    float bb = b2p[wv * 32 + n * 16 + lr];
    #pragma unroll
    for (int m = 0; m < 8; ++m)
      #pragma unroll
      for (int r = 0; r < 4; ++r) {
        float v = acc[m][n][r] + bb;
        v = v > 0.f ? v : 0.f;
        int row = m * 16 + r0 + r;
        int col = (wv * 32 + n * 16 + lr) ^ (((row >> 2) & 7) << 3);
        hbuf[row * LDH + col] = f2bf(v);
      }
  }

  // ---- preload w3 fragments for GEMM3 ----
  const int wm = wv & 3;   // m-pair: m-frags {2wm, 2wm+1}
  const int wn = wv >> 2;  // n-pair: ch {wn*32 .. wn*32+31}
  short8 w3f[8][2];
  #pragma unroll
  for (int ks = 0; ks < 8; ++ks)
    #pragma unroll
    for (int j = 0; j < 2; ++j)
      w3f[ks][j] = *(const short8*)(w3b + (wn * 32 + j * 16 + lr) * 256 + ks * 32 + lk);
  #pragma unroll
  for (int ks = 0; ks < 8; ++ks) { KEEP(w3f[ks][0]); KEEP(w3f[ks][1]); }
  __syncthreads();  // S7

  // ---- GEMM3: h2 x w3b -> logits ----
  {
    f32x4 acc3[2][2];
    f32x4 z = {0.f, 0.f, 0.f, 0.f};
    acc3[0][0] = z; acc3[0][1] = z; acc3[1][0] = z; acc3[1][1] = z;
    #pragma unroll
    for (int ks = 0; ks < 8; ++ks) {
      #pragma unroll
      for (int mi = 0; mi < 2; ++mi) {
        int row = (wm * 2 + mi) * 16 + lr;
        int g = (ks * 4 + (lane >> 4)) ^ ((row >> 2) & 7);
        short8 av = *(const short8*)(&hbuf[row * LDH + g * 8]);
        #pragma unroll
        for (int j = 0; j < 2; ++j)
          acc3[mi][j] = __builtin_amdgcn_mfma_f32_16x16x32_bf16(av, w3f[ks][j], acc3[mi][j], 0, 0, 0);
      }
    }
    #pragma unroll
    for (int j = 0; j < 2; ++j) {
      int c = wn * 32 + j * 16 + lr;
      if (c < 50) {
        float b3v = b3p[c];
        #pragma unroll
        for (int mi = 0; mi < 2; ++mi)
          #pragma unroll
          for (int r = 0; r < 4; ++r) {
            int row = n0 + (wm * 2 + mi) * 16 + r0 + r;
            out[(b * 8192 + row) * 50 + c] = acc3[mi][j][r] + b3v;
          }
      }
    }
  }
}

extern "C" void kernel_launch(void* const* d_in, const int* in_sizes, int n_in,
                              void* d_out, int out_size, void* d_ws, size_t ws_size,
                              hipStream_t stream) {
  const float* features  = (const float*)d_in[0];
  const float* centers   = (const float*)d_in[1];
  const float* pc        = (const float*)d_in[2];
  const int*   category  = (const int*)d_in[3];
  const float* cat_embed = (const float*)d_in[4];
  const float* w1  = (const float*)d_in[5];
  const float* b1  = (const float*)d_in[6];
  const float* g1  = (const float*)d_in[7];
  const float* be1 = (const float*)d_in[8];
  const float* m1  = (const float*)d_in[9];
  const float* v1  = (const float*)d_in[10];
  const float* w2  = (const float*)d_in[11];
  const float* b2  = (const float*)d_in[12];
  const float* g2  = (const float*)d_in[13];
  const float* be2 = (const float*)d_in[14];
  const float* m2  = (const float*)d_in[15];
  const float* v2  = (const float*)d_in[16];
  const float* w3  = (const float*)d_in[17];
  const float* b3  = (const float*)d_in[18];
  float* out = (float*)d_out;

  char* ws = (char*)d_ws;
  u16*   w1b   = (u16*)(ws);              // 245760 B
  u16*   w2b   = (u16*)(ws + 245760);     // 131072 B
  u16*   w3b   = (u16*)(ws + 376832);     //  32768 B
  float* b1p   = (float*)(ws + 409600);   //   1024 B
  float* b2p   = (float*)(ws + 410624);   //   1024 B
  float* b3p   = (float*)(ws + 411648);   //   1024 B (256 used)
  u16*   G     = (u16*)(ws + 412672);     // 786432 B
  float* bias1 = (float*)(ws + 1199104);  //  16384 B -> ends 1215488

  prep_kernel<<<480, TPB, 0, stream>>>(w1, b1, g1, be1, m1, v1,
                                       w2, b2, g2, be2, m2, v2,
                                       w3, b3, w1b, w2b, w3b, b1p, b2p, b3p);
  gcalc_kernel<<<32, 512, 0, stream>>>(features, category, cat_embed, w1b, b1p, G, bias1);

  fused_kernel<<<1024, 512, 0, stream>>>(centers, pc, G, bias1,
                                         w2b, w3b, b2p, b3p, out);
}

// Round 5
// 167.339 us; speedup vs baseline: 1.5714x; 1.0067x over previous
//
#include <hip/hip_runtime.h>

#define TPB 256

typedef unsigned short u16;
typedef unsigned int u32;
typedef short short8 __attribute__((ext_vector_type(8)));
typedef float f32x4 __attribute__((ext_vector_type(4)));

#define KEEP(x) asm volatile("" :: "v"(x))
#define PIN(x)  asm volatile("" : "+v"(x))

__device__ __forceinline__ u16 f2bf(float x) {
  union { float f; u32 u; } v;
  v.f = x;
  u32 r = v.u + 0x7FFFu + ((v.u >> 16) & 1u);
  return (u16)(r >> 16);
}

__device__ __forceinline__ float bf2f(u16 x) {
  union { u32 u; float f; } v;
  v.u = ((u32)x) << 16;
  return v.f;
}

// ---------------- prep: fold BN into bf16 weights + bf16-ize features ----------------
// w1b: [256][480] (cols>=451 zero), w2b: [256][256], w3b: [64][256] (rows>=50 zero),
// Fbf: [16][64][384] bf16
__global__ void prep_kernel(const float* __restrict__ w1, const float* __restrict__ b1,
                            const float* __restrict__ g1, const float* __restrict__ be1,
                            const float* __restrict__ m1, const float* __restrict__ v1,
                            const float* __restrict__ w2, const float* __restrict__ b2,
                            const float* __restrict__ g2, const float* __restrict__ be2,
                            const float* __restrict__ m2, const float* __restrict__ v2,
                            const float* __restrict__ w3, const float* __restrict__ b3,
                            const float* __restrict__ features,
                            u16* __restrict__ w1b, u16* __restrict__ w2b, u16* __restrict__ w3b,
                            float* __restrict__ b1p, float* __restrict__ b2p, float* __restrict__ b3p,
                            u16* __restrict__ Fbf)
{
  int i = blockIdx.x * TPB + threadIdx.x;
  if (i < 256 * 480) {
    int o = i / 480;
    int k = i - o * 480;
    float s = g1[o] * rsqrtf(v1[o] + 1e-5f);
    u16 r = 0;
    if (k < 451) r = f2bf(w1[o * 451 + k] * s);
    w1b[i] = r;
  }
  if (i < 256 * 256) {
    int o = i >> 8;
    float s = g2[o] * rsqrtf(v2[o] + 1e-5f);
    w2b[i] = f2bf(w2[i] * s);
  }
  if (i < 64 * 256) {
    int o = i >> 8;
    u16 r = 0;
    if (o < 50) r = f2bf(w3[i]);
    w3b[i] = r;
  }
  if (i < 256) {
    float s1 = g1[i] * rsqrtf(v1[i] + 1e-5f);
    b1p[i] = (b1[i] - m1[i]) * s1 + be1[i];
    float s2 = g2[i] * rsqrtf(v2[i] + 1e-5f);
    b2p[i] = (b2[i] - m2[i]) * s2 + be2[i];
  }
  if (i < 64) {
    b3p[i] = (i < 50) ? b3[i] : 0.f;
  }
  if (i < 98304) {  // 16*64*384/4
    f32x4 v = ((const f32x4*)features)[i];
    u32 lo = (u32)f2bf(v[0]) | ((u32)f2bf(v[1]) << 16);
    u32 hi = (u32)f2bf(v[2]) | ((u32)f2bf(v[3]) << 16);
    *(uint2*)&Fbf[i * 4] = make_uint2(lo, hi);
  }
}

// ---------------- gcalc v2: G[b][o][k] = sum_d F[b][k][d]*w1s[o][d] (k<64), no LDS ----
// 256 blocks = 16 batches x 16 ch-groups; 4 waves; wave wv = center-frag wv.
// Tail cols 64..66 = pc weights, 67..95 = 0. bias1[b][o] = b1p[o] + cat-dot.
__global__ __launch_bounds__(256, 8)
void gcalc_kernel(const u16* __restrict__ Fbf, const int* __restrict__ category,
                  const float* __restrict__ cat_embed, const u16* __restrict__ w1b,
                  const float* __restrict__ b1p,
                  u16* __restrict__ G, float* __restrict__ bias1)
{
  const int b    = blockIdx.x >> 4;
  const int og   = blockIdx.x & 15;
  const int tid  = threadIdx.x;
  const int lane = tid & 63;
  const int wv   = tid >> 6;           // m-frag (centers wv*16..wv*16+15)
  const int lr   = lane & 15;
  const int lk   = (lane >> 4) * 8;
  const int r0   = (lane >> 4) * 4;
  const u16* Fb  = Fbf + b * 24576;
  const int ch   = og * 16 + lr;

  f32x4 acc = {0.f, 0.f, 0.f, 0.f};
  #pragma unroll
  for (int ks = 0; ks < 12; ++ks) {
    short8 av = *(const short8*)(Fb + (wv * 16 + lr) * 384 + ks * 32 + lk);
    short8 bv = *(const short8*)(w1b + ch * 480 + ks * 32 + lk);
    acc = __builtin_amdgcn_mfma_f32_16x16x32_bf16(av, bv, acc, 0, 0, 0);
  }
  #pragma unroll
  for (int r = 0; r < 4; ++r)
    G[(b * 256 + ch) * 96 + wv * 16 + r0 + r] = f2bf(acc[r]);

  if (tid < 16) {
    int o = og * 16 + tid;
    const u16* wr = w1b + o * 480 + 384;
    const float* ce = cat_embed + category[b] * 64;
    float a = b1p[o];
    #pragma unroll 8
    for (int j = 0; j < 64; ++j) a += bf2f(wr[j]) * ce[j];
    bias1[b * 256 + o] = a;
    u16* Go = G + (b * 256 + o) * 96;
    Go[64] = wr[64]; Go[65] = wr[65]; Go[66] = wr[66];
    #pragma unroll
    for (int k = 67; k < 96; ++k) Go[k] = 0;
  }
}

// ---------------- fused main kernel ----------------
// One block = 128 points, 512 threads = 8 waves.
// knn -> P_ext[128][96] in LDS. GEMM1: P_ext x G (K=96) -> h1 (+bias1, relu).
// GEMM2 -> h2 (+b2p, relu). GEMM3 -> logits staged f32 in LDS -> coalesced store.
// h-buffer XOR-swizzled: col ^= ((row>>2)&7)<<3 (u16), g ^= (row>>2)&7 (b128).
#define LDP 104
#define LDH 264

__global__ __launch_bounds__(512, 4)
void fused_kernel(const float* __restrict__ centers, const float* __restrict__ pc,
                  const u16* __restrict__ G, const float* __restrict__ bias1,
                  const u16* __restrict__ w2b, const u16* __restrict__ w3b,
                  const float* __restrict__ b2p, const float* __restrict__ b3p,
                  float* __restrict__ out)
{
  __shared__ u16 hbuf[128 * LDH];   // 67584 B; aliases: P_ext @0, knn scr @32768, logits @0
  __shared__ float centl[192];
  __shared__ float pcl[384];

  const int bx   = blockIdx.x;
  const int b    = bx >> 6;
  const int n0   = (bx & 63) << 7;
  const int tid  = threadIdx.x;
  const int lane = tid & 63;
  const int wv   = tid >> 6;
  const int lr   = lane & 15;
  const int lk   = (lane >> 4) * 8;
  const int r0   = (lane >> 4) * 4;

  u16*   Pm   = hbuf;                              // [128][LDP]
  float* scrd = (float*)((char*)hbuf + 32768);     // [512][3]
  int*   scri = (int*)((char*)hbuf + 40960);       // [512][3]

  // ---- preload this wave's G fragments (complete during knn) ----
  short8 bvG[3][2];
  #pragma unroll
  for (int ks = 0; ks < 3; ++ks)
    #pragma unroll
    for (int n = 0; n < 2; ++n)
      bvG[ks][n] = *(const short8*)(G + (b * 256 + wv * 32 + n * 16 + lr) * 96 + ks * 32 + lk);

  // ---- zero P_ext + stage centers/pc ----
  {
    u32* Pw = (u32*)Pm;
    #pragma unroll
    for (int i = 0; i < 13; ++i) Pw[tid + 512 * i] = 0;
  }
  if (tid < 192) centl[tid] = centers[b * 192 + tid];
  if (tid < 384) pcl[tid] = pc[(b * 8192 + n0) * 3 + tid];
  __syncthreads();  // S1

  // ---- knn scan: 4 threads/point, 16 centers each ----
  {
    int p = tid >> 2, c = tid & 3;
    float px = pcl[p * 3 + 0], py = pcl[p * 3 + 1], pz = pcl[p * 3 + 2];
    float p2 = px * px + py * py + pz * pz;
    float bd0 = 3.4e38f, bd1 = 3.4e38f, bd2 = 3.4e38f;
    int bi0 = 0, bi1 = 0, bi2 = 0;
    int j0 = c * 16;
    for (int j = j0; j < j0 + 16; ++j) {
      float cx = centl[j * 3 + 0], cy = centl[j * 3 + 1], cz = centl[j * 3 + 2];
      float dotv = px * cx + py * cy + pz * cz;
      float c2 = cx * cx + cy * cy + cz * cz;
      float d2 = (p2 + c2) - 2.f * dotv;
      if (d2 < bd2) {
        if (d2 < bd1) {
          if (d2 < bd0) { bd2 = bd1; bi2 = bi1; bd1 = bd0; bi1 = bi0; bd0 = d2; bi0 = j; }
          else          { bd2 = bd1; bi2 = bi1; bd1 = d2; bi1 = j; }
        } else          { bd2 = d2; bi2 = j; }
      }
    }
    scrd[tid * 3 + 0] = bd0; scrd[tid * 3 + 1] = bd1; scrd[tid * 3 + 2] = bd2;
    scri[tid * 3 + 0] = bi0; scri[tid * 3 + 1] = bi1; scri[tid * 3 + 2] = bi2;
  }
  __syncthreads();  // S2

  // ---- merge + scatter interp weights & pc into P_ext ----
  if (tid < 128) {
    float bd0 = 3.4e38f, bd1 = 3.4e38f, bd2 = 3.4e38f;
    int bi0 = 0, bi1 = 0, bi2 = 0;
    #pragma unroll
    for (int c = 0; c < 4; ++c) {
      int t = tid * 4 + c;
      #pragma unroll
      for (int s = 0; s < 3; ++s) {
        float d2 = scrd[t * 3 + s];
        int   j  = scri[t * 3 + s];
        if (d2 < bd2) {
          if (d2 < bd1) {
            if (d2 < bd0) { bd2 = bd1; bi2 = bi1; bd1 = bd0; bi1 = bi0; bd0 = d2; bi0 = j; }
            else          { bd2 = bd1; bi2 = bi1; bd1 = d2; bi1 = j; }
          } else          { bd2 = d2; bi2 = j; }
        }
      }
    }
    float dd0 = sqrtf(fmaxf(bd0, 1e-12f));
    float dd1 = sqrtf(fmaxf(bd1, 1e-12f));
    float dd2 = sqrtf(fmaxf(bd2, 1e-12f));
    float u0 = 1.f / (dd0 + 1e-8f);
    float u1 = 1.f / (dd1 + 1e-8f);
    float u2 = 1.f / (dd2 + 1e-8f);
    float inv = 1.f / (u0 + u1 + u2);
    u16* Pr = Pm + tid * LDP;
    Pr[bi0] = f2bf(u0 * inv);
    Pr[bi1] = f2bf(u1 * inv);
    Pr[bi2] = f2bf(u2 * inv);
    Pr[64] = f2bf(pcl[tid * 3 + 0]);
    Pr[65] = f2bf(pcl[tid * 3 + 1]);
    Pr[66] = f2bf(pcl[tid * 3 + 2]);
  }
  KEEP(bvG[0][0]); KEEP(bvG[0][1]); KEEP(bvG[1][0]);
  KEEP(bvG[1][1]); KEEP(bvG[2][0]); KEEP(bvG[2][1]);
  __syncthreads();  // S3
  PIN(bvG[0][0]); PIN(bvG[0][1]); PIN(bvG[1][0]);
  PIN(bvG[1][1]); PIN(bvG[2][0]); PIN(bvG[2][1]);

  // ---- GEMM1: P_ext [128][96] x G-stripe -> 32 ch/wave ----
  f32x4 acc[8][2];
  {
    f32x4 z = {0.f, 0.f, 0.f, 0.f};
    #pragma unroll
    for (int m = 0; m < 8; ++m) { acc[m][0] = z; acc[m][1] = z; }
  }
  #pragma unroll
  for (int ks = 0; ks < 3; ++ks) {
    short8 av[8];
    #pragma unroll
    for (int m = 0; m < 8; ++m)
      av[m] = *(const short8*)(&Pm[(m * 16 + lr) * LDP + ks * 32 + lk]);
    #pragma unroll
    for (int m = 0; m < 8; ++m)
      #pragma unroll
      for (int n = 0; n < 2; ++n)
        acc[m][n] = __builtin_amdgcn_mfma_f32_16x16x32_bf16(av[m], bvG[ks][n], acc[m][n], 0, 0, 0);
  }
  __syncthreads();  // S4 (P_ext dead)

  // ---- epilogue 1: bias1 + relu -> h1 (swizzled) ----
  #pragma unroll
  for (int n = 0; n < 2; ++n) {
    float bb = bias1[b * 256 + wv * 32 + n * 16 + lr];
    #pragma unroll
    for (int m = 0; m < 8; ++m)
      #pragma unroll
      for (int r = 0; r < 4; ++r) {
        float v = acc[m][n][r] + bb;
        v = v > 0.f ? v : 0.f;
        int row = m * 16 + r0 + r;
        int col = (wv * 32 + n * 16 + lr) ^ (((row >> 2) & 7) << 3);
        hbuf[row * LDH + col] = f2bf(v);
      }
  }

  // ---- preload first 2 k-steps of w2 across S5 ----
  short8 w2f[2][2];
  #pragma unroll
  for (int ks = 0; ks < 2; ++ks)
    #pragma unroll
    for (int n = 0; n < 2; ++n)
      w2f[ks][n] = *(const short8*)(w2b + (wv * 32 + n * 16 + lr) * 256 + ks * 32 + lk);
  KEEP(w2f[0][0]); KEEP(w2f[0][1]); KEEP(w2f[1][0]); KEEP(w2f[1][1]);
  __syncthreads();  // S5
  PIN(w2f[0][0]); PIN(w2f[0][1]); PIN(w2f[1][0]); PIN(w2f[1][1]);

  // ---- GEMM2: h1 [128][256] x w2b-stripe -> h2 ----
  {
    f32x4 z = {0.f, 0.f, 0.f, 0.f};
    #pragma unroll
    for (int m = 0; m < 8; ++m) { acc[m][0] = z; acc[m][1] = z; }
  }
  #pragma unroll
  for (int ks = 0; ks < 8; ++ks) {
    short8 bv[2];
    if (ks < 2) { bv[0] = w2f[ks][0]; bv[1] = w2f[ks][1]; }
    else {
      #pragma unroll
      for (int n = 0; n < 2; ++n)
        bv[n] = *(const short8*)(w2b + (wv * 32 + n * 16 + lr) * 256 + ks * 32 + lk);
    }
    short8 av[8];
    #pragma unroll
    for (int m = 0; m < 8; ++m) {
      int row = m * 16 + lr;
      int g = (ks * 4 + (lane >> 4)) ^ ((row >> 2) & 7);
      av[m] = *(const short8*)(&hbuf[row * LDH + g * 8]);
    }
    #pragma unroll
    for (int m = 0; m < 8; ++m)
      #pragma unroll
      for (int n = 0; n < 2; ++n)
        acc[m][n] = __builtin_amdgcn_mfma_f32_16x16x32_bf16(av[m], bv[n], acc[m][n], 0, 0, 0);
  }
  __syncthreads();  // S6

  // ---- epilogue 2: b2p + relu -> h2 in place (swizzled) ----
  #pragma unroll
  for (int n = 0; n < 2; ++n) {
    float bb = b2p[wv * 32 + n * 16 + lr];
    #pragma unroll
    for (int m = 0; m < 8; ++m)
      #pragma unroll
      for (int r = 0; r < 4; ++r) {
        float v = acc[m][n][r] + bb;
        v = v > 0.f ? v : 0.f;
        int row = m * 16 + r0 + r;
        int col = (wv * 32 + n * 16 + lr) ^ (((row >> 2) & 7) << 3);
        hbuf[row * LDH + col] = f2bf(v);
      }
  }

  // ---- preload w3 fragments across S7 ----
  const int wm = wv & 3;
  const int wn = wv >> 2;
  short8 w3f[8][2];
  #pragma unroll
  for (int ks = 0; ks < 8; ++ks)
    #pragma unroll
    for (int j = 0; j < 2; ++j)
      w3f[ks][j] = *(const short8*)(w3b + (wn * 32 + j * 16 + lr) * 256 + ks * 32 + lk);
  #pragma unroll
  for (int ks = 0; ks < 8; ++ks) { KEEP(w3f[ks][0]); KEEP(w3f[ks][1]); }
  __syncthreads();  // S7
  #pragma unroll
  for (int ks = 0; ks < 8; ++ks) { PIN(w3f[ks][0]); PIN(w3f[ks][1]); }

  // ---- GEMM3: h2 x w3b -> logits (regs) ----
  f32x4 acc3[2][2];
  {
    f32x4 z = {0.f, 0.f, 0.f, 0.f};
    acc3[0][0] = z; acc3[0][1] = z; acc3[1][0] = z; acc3[1][1] = z;
  }
  #pragma unroll
  for (int ks = 0; ks < 8; ++ks) {
    #pragma unroll
    for (int mi = 0; mi < 2; ++mi) {
      int row = (wm * 2 + mi) * 16 + lr;
      int g = (ks * 4 + (lane >> 4)) ^ ((row >> 2) & 7);
      short8 av = *(const short8*)(&hbuf[row * LDH + g * 8]);
      #pragma unroll
      for (int j = 0; j < 2; ++j)
        acc3[mi][j] = __builtin_amdgcn_mfma_f32_16x16x32_bf16(av, w3f[ks][j], acc3[mi][j], 0, 0, 0);
    }
  }
  __syncthreads();  // S8 (all GEMM3 reads of hbuf done)

  // ---- stage logits f32 in LDS [128][52], then coalesced store ----
  {
    float* logb = (float*)hbuf;
    #pragma unroll
    for (int j = 0; j < 2; ++j) {
      int c = wn * 32 + j * 16 + lr;
      if (c < 50) {
        float b3v = b3p[c];
        #pragma unroll
        for (int mi = 0; mi < 2; ++mi)
          #pragma unroll
          for (int r = 0; r < 4; ++r) {
            int row = (wm * 2 + mi) * 16 + r0 + r;
            logb[row * 52 + c] = acc3[mi][j][r] + b3v;
          }
      }
    }
    __syncthreads();  // S9
    float* outb = out + (size_t)(b * 8192 + n0) * 50;
    #pragma unroll
    for (int i = 0; i < 13; ++i) {
      int f = tid + i * 512;
      if (f < 6400) {
        int row = (f * 5243) >> 18;   // f/50 for f<43690
        int c = f - row * 50;
        outb[f] = logb[row * 52 + c];
      }
    }
  }
}

extern "C" void kernel_launch(void* const* d_in, const int* in_sizes, int n_in,
                              void* d_out, int out_size, void* d_ws, size_t ws_size,
                              hipStream_t stream) {
  const float* features  = (const float*)d_in[0];
  const float* centers   = (const float*)d_in[1];
  const float* pc        = (const float*)d_in[2];
  const int*   category  = (const int*)d_in[3];
  const float* cat_embed = (const float*)d_in[4];
  const float* w1  = (const float*)d_in[5];
  const float* b1  = (const float*)d_in[6];
  const float* g1  = (const float*)d_in[7];
  const float* be1 = (const float*)d_in[8];
  const float* m1  = (const float*)d_in[9];
  const float* v1  = (const float*)d_in[10];
  const float* w2  = (const float*)d_in[11];
  const float* b2  = (const float*)d_in[12];
  const float* g2  = (const float*)d_in[13];
  const float* be2 = (const float*)d_in[14];
  const float* m2  = (const float*)d_in[15];
  const float* v2  = (const float*)d_in[16];
  const float* w3  = (const float*)d_in[17];
  const float* b3  = (const float*)d_in[18];
  float* out = (float*)d_out;

  char* ws = (char*)d_ws;
  u16*   w1b   = (u16*)(ws);              // 245760 B
  u16*   w2b   = (u16*)(ws + 245760);     // 131072 B
  u16*   w3b   = (u16*)(ws + 376832);     //  32768 B
  float* b1p   = (float*)(ws + 409600);   //   1024 B
  float* b2p   = (float*)(ws + 410624);   //   1024 B
  float* b3p   = (float*)(ws + 411648);   //   1024 B (256 used)
  u16*   G     = (u16*)(ws + 412672);     // 786432 B
  float* bias1 = (float*)(ws + 1199104);  //  16384 B
  u16*   Fbf   = (u16*)(ws + 1215488);    // 786432 B -> ends ~2.0 MB

  prep_kernel<<<480, TPB, 0, stream>>>(w1, b1, g1, be1, m1, v1,
                                       w2, b2, g2, be2, m2, v2,
                                       w3, b3, features,
                                       w1b, w2b, w3b, b1p, b2p, b3p, Fbf);
  gcalc_kernel<<<256, 256, 0, stream>>>(Fbf, category, cat_embed, w1b, b1p, G, bias1);

  fused_kernel<<<1024, 512, 0, stream>>>(centers, pc, G, bias1,
                                         w2b, w3b, b2p, b3p, out);
}